// Round 15
// baseline (38.280 us; speedup 1.0000x reference)
//
#include <hip/hip_runtime.h>

// QueryAndGroup: ball_query(r=0.2, nsample=32) + group xyz (centered) + group features.
// B=4, N=16384, M=2048, C=64. Output (B, 67, M, 32) f32.
//
// R13 fused = 34.7us = prep 5.5 (serialized) + qg 29 (vs ~14 floor). This round
// splits to (K1 = transpose-roles || scan-roles, K2 = pure gather):
//  - K1 hides the transpose under the scan (roles independent; scan never reads
//    featT). Kernel boundary = the global ordering the gather needs.
//  - K2 is a pure streaming gather with ALL accumulated fixes (preload row,
//    nt output stores, XCD-batch swizzle) that R2's failed split lacked.
//  - xyz4 dropped (R10: neutral); scan reads raw xyz; K1 writes idx (1MB,
//    plain stores -> L2-hot for K2) + the 3 centered-xyz channels.
// Also a decomposition experiment: K1 vs K2 timing localizes the ~11us that
// R10-R13's micro-levers couldn't explain.

typedef float vf4 __attribute__((ext_vector_type(4)));

constexpr int Bc = 4, Nc = 16384, Mc = 2048, Cc = 64, Sc = 32;
constexpr int NQ = Bc * Mc;            // 8192 queries
constexpr int TB = (Nc / 64) * Bc;     // 1024 transpose blocks
constexpr int SB = NQ / 4;             // 2048 scan blocks (WPB=4)

__global__ __launch_bounds__(256) void k1_prep_scan(
    const float* __restrict__ xyz,      // (B, N, 3)
    const float* __restrict__ new_xyz,  // (B, M, 3)
    const float* __restrict__ feat,     // (B, C, N)
    float* __restrict__ featT,          // (B, N, C)
    int* __restrict__ idxws,            // (B*M, 32)
    float* __restrict__ out)            // (B, 67, M, 32); writes channels 0..2
{
#pragma clang fp contract(off)
    __shared__ float tile[64][65];
    __shared__ int sidx[4][Sc];

    if (blockIdx.x < TB) {
        // ---- transpose role ----
        const int b = blockIdx.x >> 8;
        const int nbase = (blockIdx.x & 255) * 64;
        const int tn = threadIdx.x & 63;
        const int tq = threadIdx.x >> 6;
        const float* fb = feat + (size_t)b * Cc * Nc;
        float* ob = featT + (size_t)b * Nc * Cc;
        #pragma unroll
        for (int k = 0; k < 16; ++k) {
            const int c = k * 4 + tq;
            tile[tn][c] = fb[(size_t)c * Nc + nbase + tn];      // coalesced reads
        }
        __syncthreads();
        #pragma unroll
        for (int k = 0; k < 16; ++k) {
            const int nl = k * 4 + tq;
            ob[(size_t)(nbase + nl) * Cc + tn] = tile[nl][tn];  // coalesced writes
        }
        return;
    }

    // ---- scan role (R5's prefetched 3-scalar scan, verbatim) ----
    const int lane = threadIdx.x & 63;
    const int wv   = threadIdx.x >> 6;
    const int q    = (blockIdx.x - TB) * 4 + wv;
    const int b    = q >> 11;
    const int m    = q & (Mc - 1);

    const float r2 = 0.2f * 0.2f;
    const float* nz = new_xyz + (size_t)(b * Mc + m) * 3;
    const float qx = nz[0], qy = nz[1], qz = nz[2];
    const float* xb = xyz + (size_t)b * Nc * 3;

    int count = 0, firstIdx = 0;
    const unsigned long long lt = (1ull << lane) - 1ull;

    float px[4], py[4], pz[4];
    #pragma unroll
    for (int u = 0; u < 4; ++u) {
        const float* pp = xb + (size_t)(u * 64 + lane) * 3;
        px[u] = pp[0]; py[u] = pp[1]; pz[u] = pp[2];
    }
    for (int base = 0; base < Nc; base += 256) {
        const int nb = (base + 256 < Nc) ? base + 256 : base;   // clamped prefetch
        float nx[4], ny[4], nzv[4];
        #pragma unroll
        for (int u = 0; u < 4; ++u) {
            const float* pp = xb + (size_t)(nb + u * 64 + lane) * 3;
            nx[u] = pp[0]; ny[u] = pp[1]; nzv[u] = pp[2];
        }
        #pragma unroll
        for (int u = 0; u < 4; ++u) {
            const float dx = qx - px[u], dy = qy - py[u], dz = qz - pz[u];
            float d2 = dx * dx + dy * dy;   // no fma: match np/jax f32 rounding
            d2 = d2 + dz * dz;
            const bool in = d2 < r2;
            const unsigned long long mask = __ballot(in);
            if (in) {
                const int slot = count + __popcll(mask & lt);
                if (slot < Sc) sidx[wv][slot] = base + u * 64 + lane;
            }
            if (count == 0 && mask != 0ull)
                firstIdx = base + u * 64 + __builtin_ctzll(mask);
            count += __popcll(mask);
        }
        if (count >= Sc) break;             // wave-uniform
        #pragma unroll
        for (int u = 0; u < 4; ++u) { px[u] = nx[u]; py[u] = ny[u]; pz[u] = nzv[u]; }
    }
    {
        const int start = count < Sc ? count : Sc;
        if (start + lane < Sc) sidx[wv][start + lane] = firstIdx;
    }
    asm volatile("s_waitcnt lgkmcnt(0)" ::: "memory");

    // idx out (plain stores: 1MB, stays L2-hot for K2's coalesced reads)
    if (lane < Sc) idxws[(size_t)q * Sc + lane] = sidx[wv][lane];

    // centered-xyz channels 0..2 (nt: streamed, not re-read)
    const int s     = lane & 31;
    const int chalf = lane >> 5;
    const int myid  = sidx[wv][s];
    float* ob = out + ((size_t)b * 67 * Mc + m) * Sc;
    if (chalf == 0) {
        __builtin_nontemporal_store(xb[(size_t)myid * 3 + 0] - qx,
                                    &ob[(size_t)0 * (Mc * Sc) + s]);
        __builtin_nontemporal_store(xb[(size_t)myid * 3 + 2] - qz,
                                    &ob[(size_t)2 * (Mc * Sc) + s]);
    } else {
        __builtin_nontemporal_store(xb[(size_t)myid * 3 + 1] - qy,
                                    &ob[(size_t)1 * (Mc * Sc) + s]);
    }
}

__global__ __launch_bounds__(256) void k2_gather(
    const float* __restrict__ featT,    // (B, N, C)
    const int* __restrict__ idxws,      // (B*M, 32)
    float* __restrict__ out)            // (B, 67, M, 32); writes channels 3..66
{
    const int lane = threadIdx.x & 63;
    const int wv   = threadIdx.x >> 6;

    // XCD-batch swizzle: batch b on XCDs {2b,2b+1}.
    const int xcd = blockIdx.x & 7;
    const int b   = xcd >> 1;
    const int m   = ((xcd & 1) << 10) + (blockIdx.x >> 3) * 4 + wv;
    const int q   = b * Mc + m;

    const int s     = lane & 31;
    const int chalf = lane >> 5;
    const int myid  = idxws[(size_t)q * Sc + s];        // coalesced, L2-hot

    // Preload the whole 256B featT row before any store.
    const float* ftb = featT + ((size_t)b * Nc + myid) * Cc;
    vf4 vr[8];
    #pragma unroll
    for (int it = 0; it < 8; ++it)
        vr[it] = *(const vf4*)(ftb + (it * 2 + chalf) * 4);

    float* ob = out + ((size_t)b * 67 * Mc + m) * Sc;
    #pragma unroll
    for (int it = 0; it < 8; ++it) {
        const int c4 = it * 2 + chalf;                  // 0..15
        #pragma unroll
        for (int k = 0; k < 4; ++k)
            __builtin_nontemporal_store(
                vr[it][k], &ob[(size_t)(3 + c4 * 4 + k) * (Mc * Sc) + s]);
    }
}

// Fallback if ws too small: fused kernel with direct (C,N) gather (same values).
__global__ __launch_bounds__(256) void qg_fallback_kernel(
    const float* __restrict__ xyz, const float* __restrict__ new_xyz,
    const float* __restrict__ feat, float* __restrict__ out)
{
#pragma clang fp contract(off)
    const int lane = threadIdx.x & 63;
    const int wv   = threadIdx.x >> 6;
    const int q    = blockIdx.x * 4 + wv;
    const int b    = q >> 11;
    const int m    = q & (Mc - 1);
    __shared__ int sidx[4][Sc];
    const float r2 = 0.2f * 0.2f;
    const float* nz = new_xyz + (size_t)(b * Mc + m) * 3;
    const float qx = nz[0], qy = nz[1], qz = nz[2];
    const float* xb = xyz + (size_t)b * Nc * 3;
    int count = 0, firstIdx = 0;
    const unsigned long long lt = (1ull << lane) - 1ull;
    for (int base = 0; base < Nc; base += 64) {
        const int i = base + lane;
        const float px = xb[i * 3], py = xb[i * 3 + 1], pz = xb[i * 3 + 2];
        const float dx = qx - px, dy = qy - py, dz = qz - pz;
        float d2 = dx * dx + dy * dy; d2 = d2 + dz * dz;
        const bool in = d2 < r2;
        const unsigned long long mask = __ballot(in);
        if (in) {
            const int slot = count + __popcll(mask & lt);
            if (slot < Sc) sidx[wv][slot] = i;
        }
        if (count == 0 && mask != 0ull) firstIdx = base + __builtin_ctzll(mask);
        count += __popcll(mask);
        if (count >= Sc) break;
    }
    const int start = count < Sc ? count : Sc;
    if (start + lane < Sc) sidx[wv][start + lane] = firstIdx;
    asm volatile("s_waitcnt lgkmcnt(0)" ::: "memory");
    const int s = lane & 31, chalf = lane >> 5;
    const int myid = sidx[wv][s];
    float* ob = out + ((size_t)b * 67 * Mc + m) * Sc;
    ob[(size_t)chalf * (Mc * Sc) + s] = xb[(size_t)myid * 3 + chalf] - (chalf ? qy : qx);
    if (chalf == 0)
        ob[(size_t)2 * (Mc * Sc) + s] = xb[(size_t)myid * 3 + 2] - qz;
    const float* fb = feat + (size_t)b * Cc * Nc;
    #pragma unroll
    for (int it = 0; it < 32; ++it) {
        const int c = it * 2 + chalf;
        ob[(size_t)(3 + c) * (Mc * Sc) + s] = fb[(size_t)c * Nc + myid];
    }
}

extern "C" void kernel_launch(void* const* d_in, const int* in_sizes, int n_in,
                              void* d_out, int out_size, void* d_ws, size_t ws_size,
                              hipStream_t stream) {
    const float* xyz     = (const float*)d_in[0];
    const float* new_xyz = (const float*)d_in[1];
    const float* feat    = (const float*)d_in[2];
    float* out           = (float*)d_out;

    const size_t featT_bytes = (size_t)Bc * Nc * Cc * sizeof(float);  // 16.8 MB
    const size_t idx_bytes   = (size_t)NQ * Sc * sizeof(int);         //  1.0 MB

    if (ws_size >= featT_bytes + idx_bytes) {
        float* featT = (float*)d_ws;
        int*   idxws = (int*)((char*)d_ws + featT_bytes);
        hipLaunchKernelGGL(k1_prep_scan, dim3(TB + SB), dim3(256), 0, stream,
                           xyz, new_xyz, feat, featT, idxws, out);
        hipLaunchKernelGGL(k2_gather, dim3(NQ / 4), dim3(256), 0, stream,
                           featT, idxws, out);
    } else {
        hipLaunchKernelGGL(qg_fallback_kernel, dim3(NQ / 4), dim3(256), 0, stream,
                           xyz, new_xyz, feat, out);
    }
}